// Round 12
// baseline (1188.182 us; speedup 1.0000x reference)
//
#include <hip/hip_runtime.h>
#include <math.h>

#define NBATCH 512
#define TSTEPS 10
#define NIMG   5120   // NBATCH*TSTEPS
#define FEAT   616
#define NEDGE  8192

__device__ __forceinline__ float sigf(float x){ return 1.f/(1.f + expf(-x)); }

// ---------------- merged prep (transposes + stats zero) + CSR build ----------------
__global__ void prep_csr_kernel(const float* __restrict__ s1wl, const float* __restrict__ s1wr,
                                const float* __restrict__ s2wl, const float* __restrict__ s2wr,
                                const float* __restrict__ wih,  const float* __restrict__ whh,
                                float* __restrict__ wlT, float* __restrict__ wrT,
                                float* __restrict__ wl2T, float* __restrict__ wr2T,
                                float* __restrict__ wihT, float* __restrict__ whhT,
                                double* __restrict__ stats,
                                const int* __restrict__ edges, int* __restrict__ row_start,
                                int* __restrict__ adj)
{
  __shared__ int cnt_s[512];
  __shared__ int scan_s[512];
  if (blockIdx.x < 213){
    int idx = blockIdx.x*512 + threadIdx.x;
    if (idx < 39424){ wlT[(idx%616)*64 + idx/616] = s1wl[idx]; return; }
    idx -= 39424;
    if (idx < 39424){ wrT[(idx%616)*64 + idx/616] = s1wr[idx]; return; }
    idx -= 39424;
    if (idx < 2048){ wl2T[(idx%64)*32 + idx/64] = s2wl[idx]; return; }
    idx -= 2048;
    if (idx < 2048){ wr2T[(idx%64)*32 + idx/64] = s2wr[idx]; return; }
    idx -= 2048;
    if (idx < 8192){ wihT[(idx%32)*256 + idx/32] = wih[idx]; return; }
    idx -= 8192;
    if (idx < 16384){ whhT[(idx%64)*256 + idx/64] = whh[idx]; return; }
    idx -= 16384;
    if (idx < 1280){ stats[idx] = 0.0; }
    return;
  }
  // ---- CSR (block 213, all 512 threads enter uniformly) ----
  const int tid = threadIdx.x;
  const int* src = edges;
  const int* dst = edges + NEDGE;
  cnt_s[tid] = 0;
  __syncthreads();
  for (int e = tid; e < NEDGE; e += 512) atomicAdd(&cnt_s[dst[e]], 1);
  __syncthreads();
  int v = cnt_s[tid];
  scan_s[tid] = v;
  __syncthreads();
  for (int off = 1; off < 512; off <<= 1){
    int add = (tid >= off) ? scan_s[tid - off] : 0;
    __syncthreads();
    scan_s[tid] += add;
    __syncthreads();
  }
  int start = scan_s[tid] - v;
  row_start[tid] = start;
  if (tid == 511) row_start[512] = scan_s[511];
  cnt_s[tid] = start;   // reuse as cursor
  __syncthreads();
  for (int e = tid; e < NEDGE; e += 512){
    int d = dst[e];
    int pos = atomicAdd(&cnt_s[d], 1);
    adj[pos] = src[e];
  }
}

// ---------------- conv1 per-thread tile: 1 row x 8 px x NC co (R7 scalar core) ----------------
template<int CIN, int NC>
__device__ __forceinline__ void conv1_tile(
    float* __restrict__ smem, const float* __restrict__ wl, const float* __restrict__ gsh,
    float* __restrict__ pooled, int img, int row, int oct, int co0,
    int pos, int CNT, int SQOFF, int pyb)
{
  constexpr int LIMG = 18*44;
  float acc[8][NC];
  #pragma unroll
  for (int i = 0; i < 8; i++)
    #pragma unroll
    for (int j = 0; j < NC; j++) acc[i][j] = 0.f;

  for (int ci = 0; ci < CIN; ci++){
    const float* lbase = &smem[ci*LIMG + row*44 + oct*8];
    float v[3][10];
    #pragma unroll
    for (int r = 0; r < 3; r++){
      const float* rp = lbase + r*44;
      const float4 a = *(const float4*)rp;
      const float4 b = *(const float4*)(rp + 4);
      const float2 c2 = *(const float2*)(rp + 8);
      v[r][0] = a.x; v[r][1] = a.y; v[r][2] = a.z; v[r][3] = a.w;
      v[r][4] = b.x; v[r][5] = b.y; v[r][6] = b.z; v[r][7] = b.w;
      v[r][8] = c2.x; v[r][9] = c2.y;
    }
    #pragma unroll
    for (int dy = 0; dy < 3; dy++)
      #pragma unroll
      for (int dx = 0; dx < 3; dx++){
        if (NC == 4){
          const float4 wv = *(const float4*)&wl[(ci*9 + dy*3 + dx)*16 + co0];
          #pragma unroll
          for (int px = 0; px < 8; px++){
            float iv = v[dy][px + dx];
            acc[px][0] += iv*wv.x; acc[px][1] += iv*wv.y;
            acc[px][2] += iv*wv.z; acc[px][3] += iv*wv.w;
          }
        } else {
          const float2 wv = *(const float2*)&wl[(ci*9 + dy*3 + dx)*16 + co0];
          #pragma unroll
          for (int px = 0; px < 8; px++){
            float iv = v[dy][px + dx];
            acc[px][0] += iv*wv.x; acc[px][1] += iv*wv.y;
          }
        }
      }
  }
  __syncthreads();   // all smem reads done; reuse as stats scratch

  #pragma unroll
  for (int cl = 0; cl < NC; cl++){
    float s = 0.f, q = 0.f;
    #pragma unroll
    for (int px = 0; px < 8; px++){
      float a = acc[px][cl];
      s += a; q += a*a;
    }
    smem[(co0 + cl)*CNT + pos]         = s;
    smem[SQOFF + (co0 + cl)*CNT + pos] = q;
  }

  const int py = pyb + (row >> 1);
  #pragma unroll
  for (int cl = 0; cl < NC; cl++){
    const bool mx = gsh[co0 + cl] >= 0.f;
    float hp[4];
    #pragma unroll
    for (int j = 0; j < 4; j++){
      float a = acc[2*j][cl], b = acc[2*j + 1][cl];
      hp[j] = mx ? fmaxf(a, b) : fminf(a, b);
    }
    float op[4];
    #pragma unroll
    for (int j = 0; j < 4; j++) op[j] = __shfl_xor(hp[j], 1, 64);
    if (!(row & 1)){
      float4 r4;
      if (mx){
        r4.x = fmaxf(hp[0], op[0]); r4.y = fmaxf(hp[1], op[1]);
        r4.z = fmaxf(hp[2], op[2]); r4.w = fmaxf(hp[3], op[3]);
      } else {
        r4.x = fminf(hp[0], op[0]); r4.y = fminf(hp[1], op[1]);
        r4.z = fminf(hp[2], op[2]); r4.w = fminf(hp[3], op[3]);
      }
      *(float4*)&pooled[(size_t)img*6400 + (co0 + cl)*400 + py*20 + oct*4] = r4;
    }
  }
}

// ---------------- conv1 body (3x3 SAME, CIN->16), SINGLE PASS, EXACT 3-STRIP (R7) ----------------
template<int CIN>
__device__ __forceinline__ void conv1_dev(float* __restrict__ smem,
                                          const float* __restrict__ in, const float* __restrict__ w,
                                          const float* __restrict__ g,
                                          double* __restrict__ stats, float* __restrict__ pooled,
                                          int bid)
{
  constexpr int LIMG = 18*44;              // per-ci strip (792 floats)
  constexpr int INTSZ = (CIN*LIMG > 2560) ? CIN*LIMG : 2560;   // stats scratch fits
  float* in_t = smem;
  float* wl   = smem + INTSZ;              // [ci][tap][16]
  float* gsh  = wl + CIN*144;
  const int tid = threadIdx.x;
  const int img = bid / 3, strip = bid % 3;
  const int y0 = strip * 16;
  const int RS = (strip < 2) ? 16 : 8;     // rows in this strip
  const int t = img % TSTEPS;
  const float* imgp = in + (size_t)img * CIN * 1600;

  if (tid < 16) gsh[tid] = g[tid];
  for (int idx = tid; idx < CIN*144; idx += 320){
    int co = idx & 15, rest = idx >> 4;
    int k = rest % 9, ci = rest / 9;
    wl[(ci*9 + k)*16 + co] = w[(co*CIN + ci)*9 + k];
  }
  {
    const int c = tid % 40, rg = tid / 40;          // rg 0..7
    #pragma unroll
    for (int ci = 0; ci < CIN; ci++){
      #pragma unroll
      for (int j = 0; j < 3; j++){
        int r = rg + 8*j;                           // 0..23
        if (r < RS + 2){
          int gy = y0 + r - 1;
          in_t[ci*LIMG + r*44 + c + 1] =
              (gy >= 0 && gy < 40) ? imgp[ci*1600 + gy*40 + c] : 0.f;
        }
      }
    }
  }
  for (int i = tid; i < CIN*18; i += 320){
    int ci = i / 18, r = i % 18;
    in_t[ci*LIMG + r*44 + 0]  = 0.f;
    in_t[ci*LIMG + r*44 + 41] = 0.f;
  }
  __syncthreads();

  int CNT, SQOFF;
  if (strip < 2){
    const int cog = tid / 80, pos = tid % 80;
    const int row = pos & 15, oct = pos >> 4;
    CNT = 80; SQOFF = 1280;
    conv1_tile<CIN, 4>(in_t, wl, gsh, pooled, img, row, oct, cog*4,
                       pos, CNT, SQOFF, strip*8);
  } else {
    const int cog = tid / 40, pos = tid % 40;
    const int row = pos & 7, oct = pos >> 3;
    CNT = 40; SQOFF = 640;
    conv1_tile<CIN, 2>(in_t, wl, gsh, pooled, img, row, oct, cog*2,
                       pos, CNT, SQOFF, 16);
  }
  __syncthreads();

  if (tid < 256){
    int co = tid >> 4, seg = tid & 15;
    float vs = 0.f, vq = 0.f;
    for (int j = seg; j < CNT; j += 16){
      vs += in_t[co*CNT + j];
      vq += in_t[SQOFF + co*CNT + j];
    }
    #pragma unroll
    for (int off = 8; off > 0; off >>= 1){
      vs += __shfl_down(vs, off, 16);
      vq += __shfl_down(vq, off, 16);
    }
    if (seg == 0){
      atomicAdd(&stats[(t*16 + co)*2 + 0], (double)vs);
      atomicAdd(&stats[(t*16 + co)*2 + 1], (double)vq);
    }
  }
}

// veg conv1 standalone
__launch_bounds__(320)
__global__ void conv1_veg_kernel(const float* __restrict__ in, const float* __restrict__ w,
                                 const float* __restrict__ g,
                                 double* __restrict__ stats, float* __restrict__ pooled)
{
  __shared__ __attribute__((aligned(16))) float smem[5*18*44 + 5*144 + 16];
  conv1_dev<5>(smem, in, w, g, stats, pooled, (int)blockIdx.x);
}

// ---------------- epi element: BN2 + relu + 4x4 avgpool for one output ----------------
template<int CO>
__device__ __forceinline__ void epi_elem(int idx, const float* __restrict__ pooled,
                                         const double* __restrict__ stats2,
                                         const float* __restrict__ g2, const float* __restrict__ be2,
                                         double invCnt2, float* __restrict__ feats, int featBase)
{
  const int q = idx % 25;
  const int rest = idx / 25;
  const int co = rest % CO, img = rest / CO;
  const int t = img % TSTEPS, n = img / TSTEPS;
  const int py = q / 5, px = q % 5;
  const float* zp = pooled + (size_t)img*6400 + co*400;
  double mean = stats2[(t*CO + co)*2] * invCnt2;
  double var  = stats2[(t*CO + co)*2 + 1] * invCnt2 - mean*mean;
  if (var < 0.0) var = 0.0;
  double scd = (double)g2[co] / sqrt(var + 1e-5);
  const float sc = (float)scd;
  const float sh = be2[co] - (float)(mean * scd);
  float s = 0.f;
  #pragma unroll
  for (int r = 0; r < 4; r++){
    const float4 v = *(const float4*)&zp[(py*4 + r)*20 + px*4];
    s += fmaxf(fmaf(v.x, sc, sh), 0.f);
    s += fmaxf(fmaf(v.y, sc, sh), 0.f);
    s += fmaxf(fmaf(v.z, sc, sh), 0.f);
    s += fmaxf(fmaf(v.w, sc, sh), 0.f);
  }
  feats[(size_t)(t*NBATCH + n)*FEAT + featBase + co*25 + q] = s * 0.0625f;
}

// ---------------- MERGED: cwsi conv1 (blocks [0,nC1)) | veg epi16 (rest, 320-thr idx) ----------------
// Independent work: conv1<1> writes pooledC; epi16 reads pooledV (z2 from conv2<16>).
__launch_bounds__(320)
__global__ void cwsi1_epi16_kernel(const float* __restrict__ cwsi, const float* __restrict__ cw1,
                                   const float* __restrict__ cg1, double* __restrict__ stC1,
                                   float* __restrict__ pooledC,
                                   const float* __restrict__ pooledV, const double* __restrict__ stV2,
                                   const float* __restrict__ vg2, const float* __restrict__ vbe2,
                                   double invCnt2, float* __restrict__ feats, int nC1)
{
  __shared__ __attribute__((aligned(16))) float smem[2560 + 144 + 16];
  const int bid = (int)blockIdx.x;
  if (bid < nC1){
    conv1_dev<1>(smem, cwsi, cw1, cg1, stC1, pooledC, bid);
  } else {
    int idx = (bid - nC1)*320 + threadIdx.x;   // 0 .. NIMG*16*25-1 exact (6400 blocks)
    epi_elem<16>(idx, pooledV, stV2, vg2, vbe2, invCnt2, feats, 0);
  }
}

// ---------------- conv2 (3x3 SAME, 16->CO on 20x20), SINGLE PASS (stride 28 for CO=16) ----------------
template<int CO>
__launch_bounds__(256)
__global__ void conv2_kernel(float* __restrict__ pooled, const float* __restrict__ w,
                             const double* __restrict__ stats1, const float* __restrict__ g1,
                             const float* __restrict__ be1, double invCnt1,
                             double* __restrict__ stats2)
{
  constexpr int R = (CO == 16) ? 2 : 1;
  constexpr int P = (20/R) * 5;                 // pixel positions: 50 or 100
  constexpr int LDSW = (CO == 16) ? 28 : 24;    // in_t row stride (floats)
  constexpr int CIMG = 22*LDSW;                 // per-ci LDS image
  __shared__ __attribute__((aligned(16))) float in_t[16*CIMG];
  __shared__ __attribute__((aligned(16))) float wl[144*CO];     // [ci][k][CO]
  __shared__ float sc1s[16], sh1s[16];
  const int tid = threadIdx.x;
  const int img = blockIdx.x;
  const int t = img % TSTEPS;
  float* ip = pooled + (size_t)img * 6400;

  if (tid < 16){
    int c = tid;
    double mean = stats1[(t*16 + c)*2] * invCnt1;
    double var  = stats1[(t*16 + c)*2 + 1] * invCnt1 - mean*mean;
    if (var < 0.0) var = 0.0;
    double sc = (double)g1[c] / sqrt(var + 1e-5);
    sc1s[c] = (float)sc;
    sh1s[c] = be1[c] - (float)(mean * sc);
  }
  __syncthreads();

  for (int idx = tid; idx < 144*CO; idx += 256){
    int co = idx % CO, rest = idx / CO;
    int k = rest % 9, ci = rest / 9;
    wl[(ci*9 + k)*CO + co] = w[(co*16 + ci)*9 + k];
  }
  for (int idx = tid; idx < 16*CIMG; idx += 256){
    int ci = idx / CIMG, rem = idx % CIMG;
    int r = rem / LDSW, cc = rem % LDSW;
    int gy = r - 1, gx = cc - 1;
    float v = 0.f;
    if (cc < 22 && gy >= 0 && gy < 20 && gx >= 0 && gx < 20)
      v = fmaxf(fmaf(ip[ci*400 + gy*20 + gx], sc1s[ci], sh1s[ci]), 0.f);
    in_t[idx] = v;
  }
  __syncthreads();

  const bool act = tid < P*(CO/4);
  const int q = tid % P, cog = tid / P;
  const int x4 = (q % 5) * 4, yb = (q / 5) * R;
  const int co0 = cog * 4;
  float acc[R][4][4];                           // [row][px][co]
  #pragma unroll
  for (int rr = 0; rr < R; rr++)
    #pragma unroll
    for (int i = 0; i < 4; i++)
      #pragma unroll
      for (int j = 0; j < 4; j++) acc[rr][i][j] = 0.f;

  if (act){
    for (int ci = 0; ci < 16; ci++){
      float v[R + 2][6];
      #pragma unroll
      for (int r = 0; r < R + 2; r++){
        const float* rp = &in_t[ci*CIMG + (yb + r)*LDSW + x4];
        const float4 a = *(const float4*)rp;
        const float2 b = *(const float2*)(rp + 4);
        v[r][0] = a.x; v[r][1] = a.y; v[r][2] = a.z; v[r][3] = a.w;
        v[r][4] = b.x; v[r][5] = b.y;
      }
      #pragma unroll
      for (int dy = 0; dy < 3; dy++)
        #pragma unroll
        for (int dx = 0; dx < 3; dx++){
          const float4 wv = *(const float4*)&wl[(ci*9 + dy*3 + dx)*CO + co0];
          #pragma unroll
          for (int rr = 0; rr < R; rr++){
            #pragma unroll
            for (int px = 0; px < 4; px++){
              float iv = v[rr + dy][px + dx];
              acc[rr][px][0] += iv*wv.x; acc[rr][px][1] += iv*wv.y;
              acc[rr][px][2] += iv*wv.z; acc[rr][px][3] += iv*wv.w;
            }
          }
        }
    }
  }
  __syncthreads();   // everyone done reading in_t (and ip); reuse both below

  if (act){
    #pragma unroll
    for (int cl = 0; cl < 4; cl++){
      float s = 0.f, qq = 0.f;
      #pragma unroll
      for (int rr = 0; rr < R; rr++)
        #pragma unroll
        for (int px = 0; px < 4; px++){
          float a = acc[rr][px][cl];
          s += a; qq += a*a;
        }
      in_t[(co0 + cl)*P + q]            = s;
      in_t[CO*P + (co0 + cl)*P + q]     = qq;
      #pragma unroll
      for (int rr = 0; rr < R; rr++){
        float4 z4;
        z4.x = acc[rr][0][cl]; z4.y = acc[rr][1][cl];
        z4.z = acc[rr][2][cl]; z4.w = acc[rr][3][cl];
        *(float4*)&ip[(co0 + cl)*400 + (yb + rr)*20 + x4] = z4;
      }
    }
  }
  __syncthreads();
  if (tid < CO*8){
    int co = tid >> 3, seg = tid & 7;
    float vs = 0.f, vq = 0.f;
    for (int j = seg; j < P; j += 8){
      vs += in_t[co*P + j];
      vq += in_t[CO*P + co*P + j];
    }
    #pragma unroll
    for (int off = 4; off > 0; off >>= 1){
      vs += __shfl_down(vs, off, 8);
      vq += __shfl_down(vq, off, 8);
    }
    if (seg == 0){
      atomicAdd(&stats2[(t*CO + co)*2 + 0], (double)vs);
      atomicAdd(&stats2[(t*CO + co)*2 + 1], (double)vq);
    }
  }
}

// ---------------- conv2 epilogue (CO=8 + emb tail), 256 threads ----------------
template<int CO>
__global__ void conv2_epi_kernel(const float* __restrict__ pooled, const double* __restrict__ stats2,
                                 const float* __restrict__ g2, const float* __restrict__ be2,
                                 double invCnt2, float* __restrict__ feats, int featBase,
                                 const int* __restrict__ irr, const float* __restrict__ emb)
{
  int idx = blockIdx.x*256 + threadIdx.x;
  if (idx >= NIMG*CO*25){
    int e = idx - NIMG*CO*25;
    if (e < NBATCH*TSTEPS*16){
      int k = e & 15;
      int nt = e >> 4;
      int t = nt % TSTEPS, n = nt / TSTEPS;
      feats[(size_t)(t*NBATCH + n)*FEAT + 600 + k] = emb[irr[nt]*16 + k];
    }
    return;
  }
  epi_elem<CO>(idx, pooled, stats2, g2, be2, invCnt2, feats, featBase);
}

// ---------------- SAGE1 with FUSED scatter-max gather (float4 vectorized) ----------------
__launch_bounds__(256)
__global__ void sage1_kernel(const float* __restrict__ feats, const int* __restrict__ row_start,
                             const int* __restrict__ adj,
                             const float* __restrict__ wlT, const float* __restrict__ wrT,
                             const float* __restrict__ bl, float* __restrict__ x1)
{
  __shared__ float xr[4][616];
  __shared__ float ar[4][616];
  __shared__ int adjs[4][192];
  const int tid = threadIdx.x;
  const int bid = blockIdx.x;
  const int row0 = bid*4;
  const int t = row0 / NBATCH, n0 = row0 % NBATCH;
  const float* fb = feats + (size_t)t*NBATCH*FEAT;

  for (int idx = tid; idx < 4*154; idx += 256){
    int r = idx / 154, f4 = idx % 154;
    *(float4*)&xr[r][f4*4] = *(const float4*)&fb[(size_t)(n0 + r)*FEAT + f4*4];
  }
  #pragma unroll
  for (int r = 0; r < 4; r++){
    int rs = row_start[n0 + r], re = row_start[n0 + r + 1];
    int deg = re - rs;
    for (int i = tid; i < deg && i < 192; i += 256) adjs[r][i] = adj[rs + i];
  }
  __syncthreads();

  #pragma unroll
  for (int r = 0; r < 4; r++){
    const int rs = row_start[n0 + r], re = row_start[n0 + r + 1];
    const int deg = re - rs;
    for (int f4 = tid; f4 < 154; f4 += 256){
      float4 m; m.x = m.y = m.z = m.w = -1e30f;
      for (int j = 0; j < deg; j++){
        int s = (j < 192) ? adjs[r][j] : adj[rs + j];
        const float4 v = *(const float4*)&fb[(size_t)s*FEAT + f4*4];
        m.x = fmaxf(m.x, v.x); m.y = fmaxf(m.y, v.y);
        m.z = fmaxf(m.z, v.z); m.w = fmaxf(m.w, v.w);
      }
      if (deg == 0){ m.x = m.y = m.z = m.w = 0.f; }
      *(float4*)&ar[r][f4*4] = m;
    }
  }
  __syncthreads();

  const int wid = tid >> 6, o = tid & 63;
  const int row = row0 + wid;
  float acc = bl[o];
  #pragma unroll 4
  for (int f = 0; f < 616; f++){
    acc += ar[wid][f]*wlT[f*64 + o] + xr[wid][f]*wrT[f*64 + o];
  }
  x1[(size_t)row*64 + o] = fmaxf(acc, 0.f);
}

// ---------------- SAGE2: 64->32 + LSTM ih-precompute ----------------
__launch_bounds__(64)
__global__ void sage2_kernel(const float* __restrict__ x1, const int* __restrict__ row_start,
                             const int* __restrict__ adj, const float* __restrict__ wl2T,
                             const float* __restrict__ wr2T, const float* __restrict__ bl2,
                             const float* __restrict__ wihT, const float* __restrict__ bih,
                             const float* __restrict__ bhh,
                             float* __restrict__ x2, float* __restrict__ pre)
{
  __shared__ float am[64], xm[64], xs[32];
  __shared__ int adjs[192];
  const int bid = blockIdx.x;
  const int t = bid / NBATCH, n = bid % NBATCH;
  const int lane = threadIdx.x;
  const int rs = row_start[n], re = row_start[n + 1];
  const int deg = re - rs;
  for (int i = lane; i < deg && i < 192; i += 64) adjs[i] = adj[rs + i];
  __syncthreads();
  const float* xb = x1 + (size_t)t*NBATCH*64;
  float m = -1e30f;
  for (int j = 0; j < deg; j++){
    int s = (j < 192) ? adjs[j] : adj[rs + j];
    m = fmaxf(m, xb[s*64 + lane]);
  }
  am[lane] = (deg > 0) ? m : 0.f;
  xm[lane] = xb[n*64 + lane];
  __syncthreads();
  if (lane < 32){
    float acc = bl2[lane];
    #pragma unroll 4
    for (int f = 0; f < 64; f++){
      acc += am[f]*wl2T[f*32 + lane] + xm[f]*wr2T[f*32 + lane];
    }
    float v = fmaxf(acc, 0.f);
    x2[(size_t)(t*NBATCH + n)*32 + lane] = v;
    xs[lane] = v;
  }
  __syncthreads();
  float* pp = pre + (size_t)(t*NBATCH + n)*256;
  #pragma unroll
  for (int j = 0; j < 4; j++){
    const int o = lane + 64*j;
    float acc = bih[o] + bhh[o];
    #pragma unroll 8
    for (int k = 0; k < 32; k++) acc += xs[k]*wihT[k*256 + o];
    pp[o] = acc;
  }
}

// ---------------- fused LSTM (per-sample) + final FC, ih precomputed ----------------
__launch_bounds__(256)
__global__ void lstm_kernel(const float* __restrict__ pre, const float* __restrict__ whhT,
                            const float* __restrict__ fcw, const float* __restrict__ fcb,
                            float* __restrict__ out)
{
  __shared__ float hb[64], cbuf[64], zb[256];
  const int n = blockIdx.x;
  const int tid = threadIdx.x;
  if (tid < 64){ hb[tid] = 0.f; cbuf[tid] = 0.f; }
  __syncthreads();
  for (int t = 0; t < TSTEPS; t++){
    float acc = pre[(size_t)(t*NBATCH + n)*256 + tid];
    #pragma unroll 8
    for (int k = 0; k < 64; k++) acc += hb[k]*whhT[k*256 + tid];
    zb[tid] = acc;
    __syncthreads();
    if (tid < 64){
      float zi = zb[tid], zf = zb[64 + tid], zg = zb[128 + tid], zo = zb[192 + tid];
      float c = sigf(zf)*cbuf[tid] + sigf(zi)*tanhf(zg);
      cbuf[tid] = c;
      hb[tid] = sigf(zo)*tanhf(c);
    }
    __syncthreads();
  }
  if (tid < 64){
    float v = hb[tid]*fcw[tid];
    #pragma unroll
    for (int off = 32; off > 0; off >>= 1) v += __shfl_down(v, off, 64);
    if (tid == 0) out[n] = v + fcb[0];
  }
}

extern "C" void kernel_launch(void* const* d_in, const int* in_sizes, int n_in,
                              void* d_out, int out_size, void* d_ws, size_t ws_size,
                              hipStream_t stream)
{
  const float* veg  = (const float*)d_in[0];
  const float* cwsi = (const float*)d_in[1];
  const int*   irr  = (const int*)d_in[2];
  const int*   eidx = (const int*)d_in[3];
  const float* vw1  = (const float*)d_in[4];
  const float* vg1  = (const float*)d_in[6];
  const float* vbe1 = (const float*)d_in[7];
  const float* vw2  = (const float*)d_in[8];
  const float* vg2  = (const float*)d_in[10];
  const float* vbe2 = (const float*)d_in[11];
  const float* cw1  = (const float*)d_in[12];
  const float* cg1  = (const float*)d_in[14];
  const float* cbe1 = (const float*)d_in[15];
  const float* cw2  = (const float*)d_in[16];
  const float* cg2  = (const float*)d_in[18];
  const float* cbe2 = (const float*)d_in[19];
  const float* emb  = (const float*)d_in[20];
  const float* s1wl = (const float*)d_in[21];
  const float* s1bl = (const float*)d_in[22];
  const float* s1wr = (const float*)d_in[23];
  const float* s2wl = (const float*)d_in[24];
  const float* s2bl = (const float*)d_in[25];
  const float* s2wr = (const float*)d_in[26];
  const float* wih  = (const float*)d_in[27];
  const float* whh  = (const float*)d_in[28];
  const float* bih  = (const float*)d_in[29];
  const float* bhh  = (const float*)d_in[30];
  const float* fcw  = (const float*)d_in[31];
  const float* fcb  = (const float*)d_in[32];
  float* out = (float*)d_out;

  // cwsi gets its own pooled buffer when ws allows -> epi16 can co-run with
  // cwsi conv1 in one merged dispatch. Fallback: serial, shared buffer.
  const bool split = ws_size >= (size_t)70000000 * 4;

  float* ws = (float*)d_ws;
  size_t off = 0;
  float* pooledV = ws + off; off += (size_t)NIMG*6400;     // 131 MB
  float* pooledC = pooledV;
  if (split){ pooledC = ws + off; off += (size_t)NIMG*6400; }
  float* feats  = ws + off; off += (size_t)NIMG*FEAT;
  float* x1     = ws + off; off += (size_t)NIMG*64;
  float* x2     = ws + off; off += (size_t)NIMG*32;
  float* pre    = ws + off; off += (size_t)NIMG*256;       // LSTM ih-precompute
  float* wlT    = ws + off; off += 39424;
  float* wrT    = ws + off; off += 39424;
  float* wl2T   = ws + off; off += 2048;
  float* wr2T   = ws + off; off += 2048;
  float* wihT   = ws + off; off += 8192;
  float* whhT   = ws + off; off += 16384;
  off = (off + 1) & ~(size_t)1;                            // 8B align for doubles
  double* stats = (double*)(ws + off); off += 2560;        // 1280 doubles
  int* row_start= (int*)(ws + off); off += 513;
  int* adj      = (int*)(ws + off); off += 8192;
  (void)in_sizes; (void)n_in; (void)out_size;

  prep_csr_kernel<<<214, 512, 0, stream>>>(s1wl, s1wr, s2wl, s2wr, wih, whh,
                                           wlT, wrT, wl2T, wr2T, wihT, whhT, stats,
                                           eidx, row_start, adj);

  double* stV1 = stats;        // conv1 veg stats
  double* stV2 = stats + 320;  // conv2 veg stats
  double* stC1 = stats + 640;  // conv1 cwsi stats
  double* stC2 = stats + 960;  // conv2 cwsi stats
  const double inv1600 = 1.0/(512.0*1600.0);
  const double inv400  = 1.0/(512.0*400.0);
  const int nC1    = NIMG*3;                 // cwsi conv1 blocks
  const int nEpi16 = NIMG*16*25/320;         // 6400 blocks exact (320 thr)
  const int nEpi8  = NIMG*8*25/256;          // 4000 blocks exact
  const int nEmb   = NBATCH*TSTEPS*16/256;   // 320 blocks exact

  // --- veg CNN front ---
  conv1_veg_kernel<<<NIMG*3, 320, 0, stream>>>(veg, vw1, vg1, stV1, pooledV);
  conv2_kernel<16><<<NIMG, 256, 0, stream>>>(pooledV, vw2, stV1, vg1, vbe1, inv1600, stV2);

  if (split){
    // veg epi16 co-dispatched with cwsi conv1 (independent buffers)
    cwsi1_epi16_kernel<<<nC1 + nEpi16, 320, 0, stream>>>(cwsi, cw1, cg1, stC1, pooledC,
                                                         pooledV, stV2, vg2, vbe2, inv400,
                                                         feats, nC1);
  } else {
    // serial fallback: epi16 first (reads pooledV z2), then cwsi conv1 overwrites
    cwsi1_epi16_kernel<<<nEpi16, 320, 0, stream>>>(cwsi, cw1, cg1, stC1, pooledC,
                                                   pooledV, stV2, vg2, vbe2, inv400,
                                                   feats, 0);
    cwsi1_epi16_kernel<<<nC1, 320, 0, stream>>>(cwsi, cw1, cg1, stC1, pooledC,
                                                pooledV, stV2, vg2, vbe2, inv400,
                                                feats, nC1);
  }

  // --- cwsi CNN back ---
  conv2_kernel<8><<<NIMG, 256, 0, stream>>>(pooledC, cw2, stC1, cg1, cbe1, inv1600, stC2);
  conv2_epi_kernel<8><<<nEpi8 + nEmb, 256, 0, stream>>>(pooledC, stC2, cg2, cbe2, inv400, feats, 400,
                                                        irr, emb);

  // --- features tail ---
  sage1_kernel<<<NIMG/4, 256, 0, stream>>>(feats, row_start, adj, wlT, wrT, s1bl, x1);
  sage2_kernel<<<NIMG, 64, 0, stream>>>(x1, row_start, adj, wl2T, wr2T, s2bl,
                                        wihT, bih, bhh, x2, pre);
  lstm_kernel<<<NBATCH, 256, 0, stream>>>(pre, whhT, fcw, fcb, out);
}

// Round 13
// 1130.651 us; speedup vs baseline: 1.0509x; 1.0509x over previous
//
#include <hip/hip_runtime.h>
#include <math.h>

#define NBATCH 512
#define TSTEPS 10
#define NIMG   5120   // NBATCH*TSTEPS
#define FEAT   616
#define NEDGE  8192

__device__ __forceinline__ float sigf(float x){ return 1.f/(1.f + expf(-x)); }

// ---------------- merged prep (transposes + stats zero) + CSR build ----------------
__global__ void prep_csr_kernel(const float* __restrict__ s1wl, const float* __restrict__ s1wr,
                                const float* __restrict__ s2wl, const float* __restrict__ s2wr,
                                const float* __restrict__ wih,  const float* __restrict__ whh,
                                float* __restrict__ wlT, float* __restrict__ wrT,
                                float* __restrict__ wl2T, float* __restrict__ wr2T,
                                float* __restrict__ wihT, float* __restrict__ whhT,
                                double* __restrict__ stats,
                                const int* __restrict__ edges, int* __restrict__ row_start,
                                int* __restrict__ adj)
{
  __shared__ int cnt_s[512];
  __shared__ int scan_s[512];
  if (blockIdx.x < 213){
    int idx = blockIdx.x*512 + threadIdx.x;
    if (idx < 39424){ wlT[(idx%616)*64 + idx/616] = s1wl[idx]; return; }
    idx -= 39424;
    if (idx < 39424){ wrT[(idx%616)*64 + idx/616] = s1wr[idx]; return; }
    idx -= 39424;
    if (idx < 2048){ wl2T[(idx%64)*32 + idx/64] = s2wl[idx]; return; }
    idx -= 2048;
    if (idx < 2048){ wr2T[(idx%64)*32 + idx/64] = s2wr[idx]; return; }
    idx -= 2048;
    if (idx < 8192){ wihT[(idx%32)*256 + idx/32] = wih[idx]; return; }
    idx -= 8192;
    if (idx < 16384){ whhT[(idx%64)*256 + idx/64] = whh[idx]; return; }
    idx -= 16384;
    if (idx < 1280){ stats[idx] = 0.0; }
    return;
  }
  // ---- CSR (block 213, all 512 threads enter uniformly) ----
  const int tid = threadIdx.x;
  const int* src = edges;
  const int* dst = edges + NEDGE;
  cnt_s[tid] = 0;
  __syncthreads();
  for (int e = tid; e < NEDGE; e += 512) atomicAdd(&cnt_s[dst[e]], 1);
  __syncthreads();
  int v = cnt_s[tid];
  scan_s[tid] = v;
  __syncthreads();
  for (int off = 1; off < 512; off <<= 1){
    int add = (tid >= off) ? scan_s[tid - off] : 0;
    __syncthreads();
    scan_s[tid] += add;
    __syncthreads();
  }
  int start = scan_s[tid] - v;
  row_start[tid] = start;
  if (tid == 511) row_start[512] = scan_s[511];
  cnt_s[tid] = start;   // reuse as cursor
  __syncthreads();
  for (int e = tid; e < NEDGE; e += 512){
    int d = dst[e];
    int pos = atomicAdd(&cnt_s[d], 1);
    adj[pos] = src[e];
  }
}

// ---------------- conv1 per-thread tile: 1 row x 8 px x NC co (R7 scalar core) ----------------
template<int CIN, int NC>
__device__ __forceinline__ void conv1_tile(
    float* __restrict__ smem, const float* __restrict__ wl, const float* __restrict__ gsh,
    float* __restrict__ pooled, int img, int row, int oct, int co0,
    int pos, int CNT, int SQOFF, int pyb)
{
  constexpr int LIMG = 18*44;
  float acc[8][NC];
  #pragma unroll
  for (int i = 0; i < 8; i++)
    #pragma unroll
    for (int j = 0; j < NC; j++) acc[i][j] = 0.f;

  for (int ci = 0; ci < CIN; ci++){
    const float* lbase = &smem[ci*LIMG + row*44 + oct*8];
    float v[3][10];
    #pragma unroll
    for (int r = 0; r < 3; r++){
      const float* rp = lbase + r*44;
      const float4 a = *(const float4*)rp;
      const float4 b = *(const float4*)(rp + 4);
      const float2 c2 = *(const float2*)(rp + 8);
      v[r][0] = a.x; v[r][1] = a.y; v[r][2] = a.z; v[r][3] = a.w;
      v[r][4] = b.x; v[r][5] = b.y; v[r][6] = b.z; v[r][7] = b.w;
      v[r][8] = c2.x; v[r][9] = c2.y;
    }
    #pragma unroll
    for (int dy = 0; dy < 3; dy++)
      #pragma unroll
      for (int dx = 0; dx < 3; dx++){
        if (NC == 4){
          const float4 wv = *(const float4*)&wl[(ci*9 + dy*3 + dx)*16 + co0];
          #pragma unroll
          for (int px = 0; px < 8; px++){
            float iv = v[dy][px + dx];
            acc[px][0] += iv*wv.x; acc[px][1] += iv*wv.y;
            acc[px][2] += iv*wv.z; acc[px][3] += iv*wv.w;
          }
        } else {
          const float2 wv = *(const float2*)&wl[(ci*9 + dy*3 + dx)*16 + co0];
          #pragma unroll
          for (int px = 0; px < 8; px++){
            float iv = v[dy][px + dx];
            acc[px][0] += iv*wv.x; acc[px][1] += iv*wv.y;
          }
        }
      }
  }
  __syncthreads();   // all smem reads done; reuse as stats scratch

  #pragma unroll
  for (int cl = 0; cl < NC; cl++){
    float s = 0.f, q = 0.f;
    #pragma unroll
    for (int px = 0; px < 8; px++){
      float a = acc[px][cl];
      s += a; q += a*a;
    }
    smem[(co0 + cl)*CNT + pos]         = s;
    smem[SQOFF + (co0 + cl)*CNT + pos] = q;
  }

  const int py = pyb + (row >> 1);
  #pragma unroll
  for (int cl = 0; cl < NC; cl++){
    const bool mx = gsh[co0 + cl] >= 0.f;
    float hp[4];
    #pragma unroll
    for (int j = 0; j < 4; j++){
      float a = acc[2*j][cl], b = acc[2*j + 1][cl];
      hp[j] = mx ? fmaxf(a, b) : fminf(a, b);
    }
    float op[4];
    #pragma unroll
    for (int j = 0; j < 4; j++) op[j] = __shfl_xor(hp[j], 1, 64);
    if (!(row & 1)){
      float4 r4;
      if (mx){
        r4.x = fmaxf(hp[0], op[0]); r4.y = fmaxf(hp[1], op[1]);
        r4.z = fmaxf(hp[2], op[2]); r4.w = fmaxf(hp[3], op[3]);
      } else {
        r4.x = fminf(hp[0], op[0]); r4.y = fminf(hp[1], op[1]);
        r4.z = fminf(hp[2], op[2]); r4.w = fminf(hp[3], op[3]);
      }
      *(float4*)&pooled[(size_t)img*6400 + (co0 + cl)*400 + py*20 + oct*4] = r4;
    }
  }
}

// ---------------- conv1 (3x3 SAME, CIN->16), SINGLE PASS, EXACT 3-STRIP (R7) ----------------
template<int CIN>
__launch_bounds__(320)
__global__ void conv1_kernel(const float* __restrict__ in, const float* __restrict__ w,
                             const float* __restrict__ g,
                             double* __restrict__ stats, float* __restrict__ pooled)
{
  constexpr int LIMG = 18*44;              // per-ci strip (792 floats)
  constexpr int INTSZ = (CIN*LIMG > 2560) ? CIN*LIMG : 2560;   // stats scratch fits
  __shared__ __attribute__((aligned(16))) float in_t[INTSZ];
  __shared__ __attribute__((aligned(16))) float wl[CIN*144];   // [ci][tap][16]
  __shared__ float gsh[16];
  const int tid = threadIdx.x;
  const int bid = blockIdx.x;
  const int img = bid / 3, strip = bid % 3;
  const int y0 = strip * 16;
  const int RS = (strip < 2) ? 16 : 8;     // rows in this strip
  const int t = img % TSTEPS;
  const float* imgp = in + (size_t)img * CIN * 1600;

  if (tid < 16) gsh[tid] = g[tid];
  for (int idx = tid; idx < CIN*144; idx += 320){
    int co = idx & 15, rest = idx >> 4;
    int k = rest % 9, ci = rest / 9;
    wl[(ci*9 + k)*16 + co] = w[(co*CIN + ci)*9 + k];
  }
  {
    const int c = tid % 40, rg = tid / 40;          // rg 0..7
    #pragma unroll
    for (int ci = 0; ci < CIN; ci++){
      #pragma unroll
      for (int j = 0; j < 3; j++){
        int r = rg + 8*j;                           // 0..23
        if (r < RS + 2){
          int gy = y0 + r - 1;
          in_t[ci*LIMG + r*44 + c + 1] =
              (gy >= 0 && gy < 40) ? imgp[ci*1600 + gy*40 + c] : 0.f;
        }
      }
    }
  }
  for (int i = tid; i < CIN*18; i += 320){
    int ci = i / 18, r = i % 18;
    in_t[ci*LIMG + r*44 + 0]  = 0.f;
    in_t[ci*LIMG + r*44 + 41] = 0.f;
  }
  __syncthreads();

  int CNT, SQOFF;
  if (strip < 2){
    const int cog = tid / 80, pos = tid % 80;
    const int row = pos & 15, oct = pos >> 4;
    CNT = 80; SQOFF = 1280;
    conv1_tile<CIN, 4>(in_t, wl, gsh, pooled, img, row, oct, cog*4,
                       pos, CNT, SQOFF, strip*8);
  } else {
    const int cog = tid / 40, pos = tid % 40;
    const int row = pos & 7, oct = pos >> 3;
    CNT = 40; SQOFF = 640;
    conv1_tile<CIN, 2>(in_t, wl, gsh, pooled, img, row, oct, cog*2,
                       pos, CNT, SQOFF, 16);
  }
  __syncthreads();

  if (tid < 256){
    int co = tid >> 4, seg = tid & 15;
    float vs = 0.f, vq = 0.f;
    for (int j = seg; j < CNT; j += 16){
      vs += in_t[co*CNT + j];
      vq += in_t[SQOFF + co*CNT + j];
    }
    #pragma unroll
    for (int off = 8; off > 0; off >>= 1){
      vs += __shfl_down(vs, off, 16);
      vq += __shfl_down(vq, off, 16);
    }
    if (seg == 0){
      atomicAdd(&stats[(t*16 + co)*2 + 0], (double)vs);
      atomicAdd(&stats[(t*16 + co)*2 + 1], (double)vq);
    }
  }
}

// ---------------- conv2 (3x3 SAME, 16->CO on 20x20), SINGLE PASS (stride 28 for CO=16) ----------------
// Staging: float4-memset in_t then fully-coalesced interior fill (all 64
// lanes contiguous over ip's 400-elem channel; same BN1 fmaf/relu on the same
// values -> LDS contents bit-identical to the idx-mapped version).
template<int CO>
__launch_bounds__(256)
__global__ void conv2_kernel(float* __restrict__ pooled, const float* __restrict__ w,
                             const double* __restrict__ stats1, const float* __restrict__ g1,
                             const float* __restrict__ be1, double invCnt1,
                             double* __restrict__ stats2)
{
  constexpr int R = (CO == 16) ? 2 : 1;
  constexpr int P = (20/R) * 5;                 // pixel positions: 50 or 100
  constexpr int LDSW = (CO == 16) ? 28 : 24;    // in_t row stride (floats)
  constexpr int CIMG = 22*LDSW;                 // per-ci LDS image
  __shared__ __attribute__((aligned(16))) float in_t[16*CIMG];
  __shared__ __attribute__((aligned(16))) float wl[144*CO];     // [ci][k][CO]
  __shared__ float sc1s[16], sh1s[16];
  const int tid = threadIdx.x;
  const int img = blockIdx.x;
  const int t = img % TSTEPS;
  float* ip = pooled + (size_t)img * 6400;

  if (tid < 16){
    int c = tid;
    double mean = stats1[(t*16 + c)*2] * invCnt1;
    double var  = stats1[(t*16 + c)*2 + 1] * invCnt1 - mean*mean;
    if (var < 0.0) var = 0.0;
    double sc = (double)g1[c] / sqrt(var + 1e-5);
    sc1s[c] = (float)sc;
    sh1s[c] = be1[c] - (float)(mean * sc);
  }
  // zero the whole tile (float4), halo/pad stays 0
  for (int i4 = tid; i4 < 16*CIMG/4; i4 += 256){
    *(float4*)&in_t[i4*4] = make_float4(0.f, 0.f, 0.f, 0.f);
  }
  for (int idx = tid; idx < 144*CO; idx += 256){
    int co = idx % CO, rest = idx / CO;
    int k = rest % 9, ci = rest / 9;
    wl[(ci*9 + k)*CO + co] = w[(co*16 + ci)*9 + k];
  }
  __syncthreads();   // sc1s ready (and zeros committed) before interior fill

  // coalesced interior fill with BN1 affine + relu
  #pragma unroll
  for (int ci = 0; ci < 16; ci++){
    const float sc = sc1s[ci], sh = sh1s[ci];
    #pragma unroll
    for (int it = 0; it < 2; it++){
      int idx2 = it*256 + tid;                 // 0..399 (it=1: 256..399 masked)
      if (idx2 < 400){
        int gy = idx2 / 20, gx = idx2 % 20;
        in_t[ci*CIMG + (gy + 1)*LDSW + gx + 1] =
            fmaxf(fmaf(ip[ci*400 + idx2], sc, sh), 0.f);
      }
    }
  }
  __syncthreads();

  const bool act = tid < P*(CO/4);
  const int q = tid % P, cog = tid / P;
  const int x4 = (q % 5) * 4, yb = (q / 5) * R;
  const int co0 = cog * 4;
  float acc[R][4][4];                           // [row][px][co]
  #pragma unroll
  for (int rr = 0; rr < R; rr++)
    #pragma unroll
    for (int i = 0; i < 4; i++)
      #pragma unroll
      for (int j = 0; j < 4; j++) acc[rr][i][j] = 0.f;

  if (act){
    for (int ci = 0; ci < 16; ci++){
      float v[R + 2][6];
      #pragma unroll
      for (int r = 0; r < R + 2; r++){
        const float* rp = &in_t[ci*CIMG + (yb + r)*LDSW + x4];
        const float4 a = *(const float4*)rp;
        const float2 b = *(const float2*)(rp + 4);
        v[r][0] = a.x; v[r][1] = a.y; v[r][2] = a.z; v[r][3] = a.w;
        v[r][4] = b.x; v[r][5] = b.y;
      }
      #pragma unroll
      for (int dy = 0; dy < 3; dy++)
        #pragma unroll
        for (int dx = 0; dx < 3; dx++){
          const float4 wv = *(const float4*)&wl[(ci*9 + dy*3 + dx)*CO + co0];
          #pragma unroll
          for (int rr = 0; rr < R; rr++){
            #pragma unroll
            for (int px = 0; px < 4; px++){
              float iv = v[rr + dy][px + dx];
              acc[rr][px][0] += iv*wv.x; acc[rr][px][1] += iv*wv.y;
              acc[rr][px][2] += iv*wv.z; acc[rr][px][3] += iv*wv.w;
            }
          }
        }
    }
  }
  __syncthreads();   // everyone done reading in_t (and ip); reuse both below

  if (act){
    #pragma unroll
    for (int cl = 0; cl < 4; cl++){
      float s = 0.f, qq = 0.f;
      #pragma unroll
      for (int rr = 0; rr < R; rr++)
        #pragma unroll
        for (int px = 0; px < 4; px++){
          float a = acc[rr][px][cl];
          s += a; qq += a*a;
        }
      in_t[(co0 + cl)*P + q]            = s;
      in_t[CO*P + (co0 + cl)*P + q]     = qq;
      #pragma unroll
      for (int rr = 0; rr < R; rr++){
        float4 z4;
        z4.x = acc[rr][0][cl]; z4.y = acc[rr][1][cl];
        z4.z = acc[rr][2][cl]; z4.w = acc[rr][3][cl];
        *(float4*)&ip[(co0 + cl)*400 + (yb + rr)*20 + x4] = z4;
      }
    }
  }
  __syncthreads();
  if (tid < CO*8){
    int co = tid >> 3, seg = tid & 7;
    float vs = 0.f, vq = 0.f;
    for (int j = seg; j < P; j += 8){
      vs += in_t[co*P + j];
      vq += in_t[CO*P + co*P + j];
    }
    #pragma unroll
    for (int off = 4; off > 0; off >>= 1){
      vs += __shfl_down(vs, off, 8);
      vq += __shfl_down(vq, off, 8);
    }
    if (seg == 0){
      atomicAdd(&stats2[(t*CO + co)*2 + 0], (double)vs);
      atomicAdd(&stats2[(t*CO + co)*2 + 1], (double)vq);
    }
  }
}

// ---------------- conv2 epilogue: BN2 + relu + 4x4 avgpool -> feats (+ emb tail) ----------------
template<int CO>
__global__ void conv2_epi_kernel(const float* __restrict__ pooled, const double* __restrict__ stats2,
                                 const float* __restrict__ g2, const float* __restrict__ be2,
                                 double invCnt2, float* __restrict__ feats, int featBase,
                                 const int* __restrict__ irr, const float* __restrict__ emb)
{
  int idx = blockIdx.x*256 + threadIdx.x;
  if (idx >= NIMG*CO*25){
    int e = idx - NIMG*CO*25;
    if (e < NBATCH*TSTEPS*16){
      int k = e & 15;
      int nt = e >> 4;
      int t = nt % TSTEPS, n = nt / TSTEPS;
      feats[(size_t)(t*NBATCH + n)*FEAT + 600 + k] = emb[irr[nt]*16 + k];
    }
    return;
  }
  const int q = idx % 25;
  const int rest = idx / 25;
  const int co = rest % CO, img = rest / CO;
  const int t = img % TSTEPS, n = img / TSTEPS;
  const int py = q / 5, px = q % 5;
  const float* zp = pooled + (size_t)img*6400 + co*400;
  double mean = stats2[(t*CO + co)*2] * invCnt2;
  double var  = stats2[(t*CO + co)*2 + 1] * invCnt2 - mean*mean;
  if (var < 0.0) var = 0.0;
  double scd = (double)g2[co] / sqrt(var + 1e-5);
  const float sc = (float)scd;
  const float sh = be2[co] - (float)(mean * scd);
  float s = 0.f;
  #pragma unroll
  for (int r = 0; r < 4; r++){
    const float4 v = *(const float4*)&zp[(py*4 + r)*20 + px*4];
    s += fmaxf(fmaf(v.x, sc, sh), 0.f);
    s += fmaxf(fmaf(v.y, sc, sh), 0.f);
    s += fmaxf(fmaf(v.z, sc, sh), 0.f);
    s += fmaxf(fmaf(v.w, sc, sh), 0.f);
  }
  feats[(size_t)(t*NBATCH + n)*FEAT + featBase + co*25 + q] = s * 0.0625f;
}

// ---------------- SAGE1 with FUSED scatter-max gather (float4 vectorized) ----------------
__launch_bounds__(256)
__global__ void sage1_kernel(const float* __restrict__ feats, const int* __restrict__ row_start,
                             const int* __restrict__ adj,
                             const float* __restrict__ wlT, const float* __restrict__ wrT,
                             const float* __restrict__ bl, float* __restrict__ x1)
{
  __shared__ float xr[4][616];
  __shared__ float ar[4][616];
  __shared__ int adjs[4][192];
  const int tid = threadIdx.x;
  const int bid = blockIdx.x;
  const int row0 = bid*4;
  const int t = row0 / NBATCH, n0 = row0 % NBATCH;
  const float* fb = feats + (size_t)t*NBATCH*FEAT;

  for (int idx = tid; idx < 4*154; idx += 256){
    int r = idx / 154, f4 = idx % 154;
    *(float4*)&xr[r][f4*4] = *(const float4*)&fb[(size_t)(n0 + r)*FEAT + f4*4];
  }
  #pragma unroll
  for (int r = 0; r < 4; r++){
    int rs = row_start[n0 + r], re = row_start[n0 + r + 1];
    int deg = re - rs;
    for (int i = tid; i < deg && i < 192; i += 256) adjs[r][i] = adj[rs + i];
  }
  __syncthreads();

  #pragma unroll
  for (int r = 0; r < 4; r++){
    const int rs = row_start[n0 + r], re = row_start[n0 + r + 1];
    const int deg = re - rs;
    for (int f4 = tid; f4 < 154; f4 += 256){
      float4 m; m.x = m.y = m.z = m.w = -1e30f;
      for (int j = 0; j < deg; j++){
        int s = (j < 192) ? adjs[r][j] : adj[rs + j];
        const float4 v = *(const float4*)&fb[(size_t)s*FEAT + f4*4];
        m.x = fmaxf(m.x, v.x); m.y = fmaxf(m.y, v.y);
        m.z = fmaxf(m.z, v.z); m.w = fmaxf(m.w, v.w);
      }
      if (deg == 0){ m.x = m.y = m.z = m.w = 0.f; }
      *(float4*)&ar[r][f4*4] = m;
    }
  }
  __syncthreads();

  const int wid = tid >> 6, o = tid & 63;
  const int row = row0 + wid;
  float acc = bl[o];
  #pragma unroll 4
  for (int f = 0; f < 616; f++){
    acc += ar[wid][f]*wlT[f*64 + o] + xr[wid][f]*wrT[f*64 + o];
  }
  x1[(size_t)row*64 + o] = fmaxf(acc, 0.f);
}

// ---------------- SAGE2: 64->32 + LSTM ih-precompute ----------------
__launch_bounds__(64)
__global__ void sage2_kernel(const float* __restrict__ x1, const int* __restrict__ row_start,
                             const int* __restrict__ adj, const float* __restrict__ wl2T,
                             const float* __restrict__ wr2T, const float* __restrict__ bl2,
                             const float* __restrict__ wihT, const float* __restrict__ bih,
                             const float* __restrict__ bhh,
                             float* __restrict__ x2, float* __restrict__ pre)
{
  __shared__ float am[64], xm[64], xs[32];
  __shared__ int adjs[192];
  const int bid = blockIdx.x;
  const int t = bid / NBATCH, n = bid % NBATCH;
  const int lane = threadIdx.x;
  const int rs = row_start[n], re = row_start[n + 1];
  const int deg = re - rs;
  for (int i = lane; i < deg && i < 192; i += 64) adjs[i] = adj[rs + i];
  __syncthreads();
  const float* xb = x1 + (size_t)t*NBATCH*64;
  float m = -1e30f;
  for (int j = 0; j < deg; j++){
    int s = (j < 192) ? adjs[j] : adj[rs + j];
    m = fmaxf(m, xb[s*64 + lane]);
  }
  am[lane] = (deg > 0) ? m : 0.f;
  xm[lane] = xb[n*64 + lane];
  __syncthreads();
  if (lane < 32){
    float acc = bl2[lane];
    #pragma unroll 4
    for (int f = 0; f < 64; f++){
      acc += am[f]*wl2T[f*32 + lane] + xm[f]*wr2T[f*32 + lane];
    }
    float v = fmaxf(acc, 0.f);
    x2[(size_t)(t*NBATCH + n)*32 + lane] = v;
    xs[lane] = v;
  }
  __syncthreads();
  float* pp = pre + (size_t)(t*NBATCH + n)*256;
  #pragma unroll
  for (int j = 0; j < 4; j++){
    const int o = lane + 64*j;
    float acc = bih[o] + bhh[o];
    #pragma unroll 8
    for (int k = 0; k < 32; k++) acc += xs[k]*wihT[k*256 + o];
    pp[o] = acc;
  }
}

// ---------------- fused LSTM (per-sample) + final FC, ih precomputed ----------------
__launch_bounds__(256)
__global__ void lstm_kernel(const float* __restrict__ pre, const float* __restrict__ whhT,
                            const float* __restrict__ fcw, const float* __restrict__ fcb,
                            float* __restrict__ out)
{
  __shared__ float hb[64], cbuf[64], zb[256];
  const int n = blockIdx.x;
  const int tid = threadIdx.x;
  if (tid < 64){ hb[tid] = 0.f; cbuf[tid] = 0.f; }
  __syncthreads();
  for (int t = 0; t < TSTEPS; t++){
    float acc = pre[(size_t)(t*NBATCH + n)*256 + tid];
    #pragma unroll 8
    for (int k = 0; k < 64; k++) acc += hb[k]*whhT[k*256 + tid];
    zb[tid] = acc;
    __syncthreads();
    if (tid < 64){
      float zi = zb[tid], zf = zb[64 + tid], zg = zb[128 + tid], zo = zb[192 + tid];
      float c = sigf(zf)*cbuf[tid] + sigf(zi)*tanhf(zg);
      cbuf[tid] = c;
      hb[tid] = sigf(zo)*tanhf(c);
    }
    __syncthreads();
  }
  if (tid < 64){
    float v = hb[tid]*fcw[tid];
    #pragma unroll
    for (int off = 32; off > 0; off >>= 1) v += __shfl_down(v, off, 64);
    if (tid == 0) out[n] = v + fcb[0];
  }
}

extern "C" void kernel_launch(void* const* d_in, const int* in_sizes, int n_in,
                              void* d_out, int out_size, void* d_ws, size_t ws_size,
                              hipStream_t stream)
{
  const float* veg  = (const float*)d_in[0];
  const float* cwsi = (const float*)d_in[1];
  const int*   irr  = (const int*)d_in[2];
  const int*   eidx = (const int*)d_in[3];
  const float* vw1  = (const float*)d_in[4];
  const float* vg1  = (const float*)d_in[6];
  const float* vbe1 = (const float*)d_in[7];
  const float* vw2  = (const float*)d_in[8];
  const float* vg2  = (const float*)d_in[10];
  const float* vbe2 = (const float*)d_in[11];
  const float* cw1  = (const float*)d_in[12];
  const float* cg1  = (const float*)d_in[14];
  const float* cbe1 = (const float*)d_in[15];
  const float* cw2  = (const float*)d_in[16];
  const float* cg2  = (const float*)d_in[18];
  const float* cbe2 = (const float*)d_in[19];
  const float* emb  = (const float*)d_in[20];
  const float* s1wl = (const float*)d_in[21];
  const float* s1bl = (const float*)d_in[22];
  const float* s1wr = (const float*)d_in[23];
  const float* s2wl = (const float*)d_in[24];
  const float* s2bl = (const float*)d_in[25];
  const float* s2wr = (const float*)d_in[26];
  const float* wih  = (const float*)d_in[27];
  const float* whh  = (const float*)d_in[28];
  const float* bih  = (const float*)d_in[29];
  const float* bhh  = (const float*)d_in[30];
  const float* fcw  = (const float*)d_in[31];
  const float* fcb  = (const float*)d_in[32];
  float* out = (float*)d_out;

  float* ws = (float*)d_ws;
  size_t off = 0;
  float* pooled = ws + off; off += (size_t)NIMG*6400;      // 131 MB; conv1 extremum, then in-place raw z2
  float* feats  = ws + off; off += (size_t)NIMG*FEAT;
  float* x1     = ws + off; off += (size_t)NIMG*64;
  float* x2     = ws + off; off += (size_t)NIMG*32;
  float* pre    = ws + off; off += (size_t)NIMG*256;       // LSTM ih-precompute
  float* wlT    = ws + off; off += 39424;
  float* wrT    = ws + off; off += 39424;
  float* wl2T   = ws + off; off += 2048;
  float* wr2T   = ws + off; off += 2048;
  float* wihT   = ws + off; off += 8192;
  float* whhT   = ws + off; off += 16384;
  off = (off + 1) & ~(size_t)1;                            // 8B align for doubles
  double* stats = (double*)(ws + off); off += 2560;        // 1280 doubles
  int* row_start= (int*)(ws + off); off += 513;
  int* adj      = (int*)(ws + off); off += 8192;
  (void)in_sizes; (void)n_in; (void)out_size; (void)ws_size;

  prep_csr_kernel<<<214, 512, 0, stream>>>(s1wl, s1wr, s2wl, s2wr, wih, whh,
                                           wlT, wrT, wl2T, wr2T, wihT, whhT, stats,
                                           eidx, row_start, adj);

  double* stV1 = stats;        // conv1 veg stats
  double* stV2 = stats + 320;  // conv2 veg stats
  double* stC1 = stats + 640;  // conv1 cwsi stats
  double* stC2 = stats + 960;  // conv2 cwsi stats
  const double inv1600 = 1.0/(512.0*1600.0);
  const double inv400  = 1.0/(512.0*400.0);
  const int nEpi16 = NIMG*16*25/256;        // 8000 blocks exact
  const int nEpi8  = NIMG*8*25/256;         // 4000 blocks exact
  const int nEmb   = NBATCH*TSTEPS*16/256;  // 320 blocks exact

  // --- veg CNN ---
  conv1_kernel<5><<<NIMG*3, 320, 0, stream>>>(veg, vw1, vg1, stV1, pooled);
  conv2_kernel<16><<<NIMG, 256, 0, stream>>>(pooled, vw2, stV1, vg1, vbe1, inv1600, stV2);
  conv2_epi_kernel<16><<<nEpi16, 256, 0, stream>>>(pooled, stV2, vg2, vbe2, inv400, feats, 0,
                                                   irr, emb);

  // --- cwsi CNN (reuses pooled buffer after veg epi has consumed it) ---
  conv1_kernel<1><<<NIMG*3, 320, 0, stream>>>(cwsi, cw1, cg1, stC1, pooled);
  conv2_kernel<8><<<NIMG, 256, 0, stream>>>(pooled, cw2, stC1, cg1, cbe1, inv1600, stC2);
  conv2_epi_kernel<8><<<nEpi8 + nEmb, 256, 0, stream>>>(pooled, stC2, cg2, cbe2, inv400, feats, 400,
                                                        irr, emb);

  // --- features tail ---
  sage1_kernel<<<NIMG/4, 256, 0, stream>>>(feats, row_start, adj, wlT, wrT, s1bl, x1);
  sage2_kernel<<<NIMG, 64, 0, stream>>>(x1, row_start, adj, wl2T, wr2T, s2bl,
                                        wihT, bih, bhh, x2, pre);
  lstm_kernel<<<NBATCH, 256, 0, stream>>>(pre, whhT, fcw, fcb, out);
}